// Round 6
// baseline (414.511 us; speedup 1.0000x reference)
//
#include <hip/hip_runtime.h>
#include <cstdint>

typedef unsigned long long u64;

// ---------------------------------------------------------------------------
// prep: (a) zero padded activation maps (blocks [0,1024))
//       (b) pack all 5 binary weight tensors, COMPLEMENTED + TRANSPOSED:
//           wpT[oc*9*Wi + tap*Wi + cw], bit i = !(w[tap][cw*64+i][oc] > 0)
//       (c) per-(oc,tap) ORIGINAL positive-weight popcounts -> corr[oc*9+tap]
//           (used for exact SAME-padding correction in bconv)
// ---------------------------------------------------------------------------
__global__ __launch_bounds__(256) void prep_kernel(
        const float* __restrict__ w2, const float* __restrict__ w3,
        const float* __restrict__ w4, const float* __restrict__ w5,
        const float* __restrict__ w6,
        u64* __restrict__ wp2, u64* __restrict__ wp3, u64* __restrict__ wp4,
        u64* __restrict__ wp5, u64* __restrict__ wp6,
        int* __restrict__ corr,
        u64* __restrict__ pz, int nz) {
    const int ZB = 1024;
    if (blockIdx.x < ZB) {
        int i = blockIdx.x * 256 + threadIdx.x;
        const int stride = ZB * 256;
        for (; i < nz; i += stride) pz[i] = 0;
        return;
    }
    int wid = ((blockIdx.x - ZB) * 256 + threadIdx.x) >> 6;
    int lane = threadIdx.x & 63;
    if (wid < 71424) {
        // ---- weight packing ----
        const float* w; u64* wp; int Wi, Cout, base;
        if      (wid <  2304) { w = w2; wp = wp2; Wi = 2; Cout = 128; base = 0; }
        else if (wid <  6912) { w = w3; wp = wp3; Wi = 2; Cout = 256; base = 2304; }
        else if (wid < 16128) { w = w4; wp = wp4; Wi = 4; Cout = 256; base = 6912; }
        else if (wid < 34560) { w = w5; wp = wp5; Wi = 4; Cout = 512; base = 16128; }
        else                  { w = w6; wp = wp6; Wi = 8; Cout = 512; base = 34560; }
        int id = wid - base;
        int oc = id % Cout;
        int tw = id / Cout;            // tap*Wi + cw
        int tap = tw / Wi, cw = tw % Wi;
        int Cin = Wi * 64;
        float v = w[((size_t)tap * Cin + cw * 64 + lane) * Cout + oc];
        u64 mask = __ballot(!(v > 0.0f));
        if (lane == 0) wp[(size_t)oc * (9 * Wi) + tap * Wi + cw] = mask;
    } else if (wid < 71424 + 14976) {
        // ---- correction popcounts: p_t = #(w>0) over Cin for (oc,tap) ----
        int id2 = wid - 71424;
        const float* w; int Wi, Cout, cbase, lo;
        if      (id2 <  1152) { w = w2; Wi = 2; Cout = 128; cbase = 0;     lo = 0; }
        else if (id2 <  3456) { w = w3; Wi = 2; Cout = 256; cbase = 1152;  lo = 1152; }
        else if (id2 <  5760) { w = w4; Wi = 4; Cout = 256; cbase = 3456;  lo = 3456; }
        else if (id2 < 10368) { w = w5; Wi = 4; Cout = 512; cbase = 5760;  lo = 5760; }
        else                  { w = w6; Wi = 8; Cout = 512; cbase = 10368; lo = 10368; }
        int lid = id2 - lo;
        int tap = lid % 9;
        int oc  = lid / 9;
        int Cin = Wi * 64;
        int cnt = 0;
        for (int cw = 0; cw < Wi; cw++) {
            float v = w[((size_t)tap * Cin + cw * 64 + lane) * Cout + oc];
            cnt += (int)__popcll(__ballot(v > 0.0f));
        }
        if (lane == 0) corr[cbase + oc * 9 + tap] = cnt;
    }
}

// ---------------------------------------------------------------------------
// conv1 (float, 3->128) + b1 + relu + bn1 -> sign bits, written into the
// PADDED 34x34x2-word p1 map. Weights in VGPRs, 8 px/thread sliding window.
// Double accumulation: sign decisions feed 5 binary layers; must be exact.
// ---------------------------------------------------------------------------
__global__ __launch_bounds__(128) void conv1_pack_kernel(
        const float* __restrict__ x, const float* __restrict__ w1,
        const float* __restrict__ b1, const float* __restrict__ s1,
        const float* __restrict__ bb1, u64* __restrict__ p1) {
    const int t = threadIdx.x;
    const int oc = t;
    const int bx = blockIdx.x;
    const int xseg = (bx & 3) << 3;    // 0,8,16,24
    const int y = (bx >> 2) & 31;
    const int b = bx >> 7;

    double wreg[27];
    #pragma unroll
    for (int k = 0; k < 27; k++) wreg[k] = (double)w1[k * 128 + oc];
    const double b1v = (double)b1[oc];
    const double tneg = -(double)bb1[oc] / (double)s1[oc];
    const bool always = tneg < 0.0;
    const double thr = tneg - b1v;

    double acc[8];
    #pragma unroll
    for (int i = 0; i < 8; i++) acc[i] = 0.0;

    #pragma unroll
    for (int ky = 0; ky < 3; ky++) {
        int iy = y - 1 + ky;
        if (iy < 0 || iy > 31) continue;
        #pragma unroll
        for (int col = 0; col < 10; col++) {
            int ix = xseg - 1 + col;
            if (ix < 0 || ix > 31) continue;
            const float* xp = x + ((b * 32 + iy) * 32 + ix) * 3;
            #pragma unroll
            for (int c = 0; c < 3; c++) {
                double xv = (double)xp[c];
                #pragma unroll
                for (int kx = 0; kx < 3; kx++) {
                    int px = col - kx;
                    if (px >= 0 && px < 8)
                        acc[px] += xv * wreg[(ky * 3 + kx) * 3 + c];
                }
            }
        }
    }
    #pragma unroll
    for (int px = 0; px < 8; px++) {
        bool bit = always || (acc[px] > thr);
        u64 m = __ballot(bit);
        if ((t & 63) == 0)
            p1[((size_t)(b * 34 + y + 1) * 34 + xseg + px + 1) * 2 + (t >> 6)] = m;
    }
}

// ---------------------------------------------------------------------------
// Binary conv v5 — LANE = PIXEL layout.
// One wave = 8x8 pre-pool pixel tile x OCG output channels.
//  * activations: per-lane 3x3xWI neighborhood loaded ONCE into VGPRs,
//    reused across all OCG channels (vector loads: 72 per wave total).
//  * weights: address depends only on the (runtime) oc loop -> guaranteed
//    wave-uniform s_load on the SMEM pipe (zero VALU).
//  * dot: pure xor + fused v_bcnt accumulate, 4 independent chains.
//  * SAME padding: exact correction d = 2*(m+S) - 64*WI*(9+n_oob),
//    S = sum of precomputed per-tap weight popcounts over this lane's OOB
//    taps (8 mads from corr[] scalars).
//  * pool: 2x shfl_xor + max (all 4 window lanes converge); masters store.
//  * output bits built per-lane (mask |= bit<<o), stored as u16/u32/u64.
// ---------------------------------------------------------------------------
template<int WI, int H, int W, int COUT, bool POOL, int OCG, bool BITOUT>
__global__ __launch_bounds__(256, (WI == 8) ? 2 : 4) void bconv5_kernel(
        const u64* __restrict__ in, const u64* __restrict__ wp,
        const int* __restrict__ corr,
        const float* __restrict__ bns, const float* __restrict__ bnb,
        u64* __restrict__ outb, float* __restrict__ outf) {
    constexpr int Hp = H + 2, Wp = W + 2;
    constexpr int Ho = POOL ? H / 2 : H;
    constexpr int Wo = POOL ? W / 2 : W;
    constexpr int WoW = COUT >> 6;
    constexpr int TY = H / 8, TX = W / 8;
    constexpr int NG = COUT / OCG;

    const int lane = threadIdx.x & 63;
    int wid = (blockIdx.x * blockDim.x + threadIdx.x) >> 6;
    wid = __builtin_amdgcn_readfirstlane(wid);
    const int g = wid % NG;
    int t2 = wid / NG;
    const int tile = t2 % (TY * TX);
    const int b = t2 / (TY * TX);
    if (b >= 128) return;
    const int ty0 = (tile / TX) * 8, tx0 = (tile % TX) * 8;
    const int ly = lane >> 3, lx = lane & 7;
    const int py = ty0 + ly, px = tx0 + lx;       // pre-pool pixel (unpadded)

    // ---- per-lane activation neighborhood (padded map: pixel -> +1) ----
    u64 act[9 * WI];
    const u64* ib = in + (((size_t)b * Hp + py) * Wp + px) * WI;
    #pragma unroll
    for (int ky = 0; ky < 3; ky++)
        #pragma unroll
        for (int kx = 0; kx < 3; kx++)
            #pragma unroll
            for (int cw = 0; cw < WI; cw++)
                act[(ky * 3 + kx) * WI + cw] = ib[((size_t)ky * Wp + kx) * WI + cw];

    // ---- per-lane edge flags ----
    const int ft = (py == 0), fb = (py == H - 1);
    const int fl = (px == 0), fr = (px == W - 1);
    const int ctl = ft & fl, ctr = ft & fr, cbl = fb & fl, cbr = fb & fr;
    const int n_oob = 3 * (ft + fb + fl + fr) - ctl - ctr - cbl - cbr;
    const int dbase = -64 * WI * (9 + n_oob);

    const int oc0 = g * OCG;
    const bool master = POOL ? (((ly | lx) & 1) == 0) : true;
    const int opy = POOL ? (py >> 1) : py, opx = POOL ? (px >> 1) : px;

    u64 mask = 0;
    #pragma unroll 1
    for (int o = 0; o < OCG; o++) {
        const int oc = oc0 + o;
        const u64* wl = wp + (size_t)oc * (9 * WI);   // uniform -> s_load
        const int* cp = corr + oc * 9;                // uniform -> s_load

        int a0 = 0, a1 = 0, a2 = 0, a3 = 0;
        #pragma unroll
        for (int ky = 0; ky < 3; ky++) {
            u64 wv[3 * WI];
            #pragma unroll
            for (int k = 0; k < 3 * WI; k++) wv[k] = wl[ky * 3 * WI + k];
            #pragma unroll
            for (int kx = 0; kx < 3; kx++)
                #pragma unroll
                for (int cw = 0; cw < WI; cw++) {
                    u64 xo = act[(ky * 3 + kx) * WI + cw] ^ wv[kx * WI + cw];
                    const int ai = (kx * WI + cw) & 3;
                    int lo = __builtin_popcount((unsigned)xo);
                    int hi = __builtin_popcount((unsigned)(xo >> 32));
                    if (ai == 0) { a0 = lo + a0; a0 = hi + a0; }
                    else if (ai == 1) { a1 = lo + a1; a1 = hi + a1; }
                    else if (ai == 2) { a2 = lo + a2; a2 = hi + a2; }
                    else { a3 = lo + a3; a3 = hi + a3; }
                }
        }
        const int m = (a0 + a1) + (a2 + a3);

        // padding correction (scalars from corr, per-lane flags)
        const int p0 = cp[0], p1_ = cp[1], p2 = cp[2], p3 = cp[3], p5 = cp[5],
                  p6 = cp[6], p7 = cp[7], p8 = cp[8];
        const int A = p0 + p1_ + p2, B = p6 + p7 + p8;
        const int C = p0 + p3 + p6, D = p2 + p5 + p8;
        int S = ft * A + fb * B + fl * C + fr * D
              - ctl * p0 - ctr * p2 - cbl * p6 - cbr * p8;
        int d = 2 * (m + S) + dbase;

        if constexpr (POOL) {
            int dm = max(d, __shfl_xor(d, 1, 64));
            d = max(dm, __shfl_xor(dm, 8, 64));
        }
        const int pmax = d > 0 ? d : 0;
        const double h = (double)pmax * (double)bns[oc] + (double)bnb[oc];
        if constexpr (BITOUT) {
            mask |= (u64)(h > 0.0) << o;
        } else {
            if (master)
                outf[((size_t)(b * Ho + opy) * Wo + opx) * COUT + oc] = (float)h;
        }
    }

    if constexpr (BITOUT) {
        if (master) {
            size_t pix = (size_t)(b * (Ho + 2) + opy + 1) * (Wo + 2) + opx + 1;
            char* bp = (char*)(outb + pix * WoW) + (oc0 >> 3);
            if constexpr (OCG == 64) *(u64*)bp = mask;
            else if constexpr (OCG == 32) *(unsigned*)bp = (unsigned)mask;
            else *(unsigned short*)bp = (unsigned short)mask;
        }
    }
}

// ---------------------------------------------------------------------------
// Dense (512x10) + softmax. One wave per row (b,y,x). 2048 rows.
// ---------------------------------------------------------------------------
__global__ __launch_bounds__(256) void dense_softmax_kernel(
        const float* __restrict__ h6, const float* __restrict__ dw,
        const float* __restrict__ db, float* __restrict__ out) {
    int lane = threadIdx.x & 63;
    int r = (blockIdx.x * blockDim.x + threadIdx.x) >> 6;
    if (r >= 2048) return;
    const float* hr = h6 + (size_t)r * 512;
    float part[10];
    #pragma unroll
    for (int d = 0; d < 10; d++) part[d] = 0.f;
    #pragma unroll
    for (int k = 0; k < 8; k++) {
        int c = lane + 64 * k;
        float hv = hr[c];
        const float* dwr = dw + c * 10;
        #pragma unroll
        for (int d = 0; d < 10; d++) part[d] += hv * dwr[d];
    }
    #pragma unroll
    for (int off = 32; off >= 1; off >>= 1) {
        #pragma unroll
        for (int d = 0; d < 10; d++) part[d] += __shfl_down(part[d], off, 64);
    }
    if (lane == 0) {
        float logits[10];
        float mx = -1e30f;
        #pragma unroll
        for (int d = 0; d < 10; d++) { logits[d] = part[d] + db[d]; mx = fmaxf(mx, logits[d]); }
        float se = 0.f;
        #pragma unroll
        for (int d = 0; d < 10; d++) { logits[d] = expf(logits[d] - mx); se += logits[d]; }
        float inv = 1.f / se;
        #pragma unroll
        for (int d = 0; d < 10; d++) out[(size_t)r * 10 + d] = logits[d] * inv;
    }
}

// ---------------------------------------------------------------------------
extern "C" void kernel_launch(void* const* d_in, const int* in_sizes, int n_in,
                              void* d_out, int out_size, void* d_ws, size_t ws_size,
                              hipStream_t stream) {
    const float* x    = (const float*)d_in[0];
    const float* w1   = (const float*)d_in[1];
    const float* b1   = (const float*)d_in[2];
    const float* w2   = (const float*)d_in[3];
    const float* w3   = (const float*)d_in[4];
    const float* w4   = (const float*)d_in[5];
    const float* w5   = (const float*)d_in[6];
    const float* w6   = (const float*)d_in[7];
    const float* bn1s = (const float*)d_in[8];
    const float* bn1b = (const float*)d_in[9];
    const float* bn2s = (const float*)d_in[10];
    const float* bn2b = (const float*)d_in[11];
    const float* bn3s = (const float*)d_in[12];
    const float* bn3b = (const float*)d_in[13];
    const float* bn4s = (const float*)d_in[14];
    const float* bn4b = (const float*)d_in[15];
    const float* bn5s = (const float*)d_in[16];
    const float* bn5b = (const float*)d_in[17];
    const float* bn6s = (const float*)d_in[18];
    const float* bn6b = (const float*)d_in[19];
    const float* dw   = (const float*)d_in[20];
    const float* db   = (const float*)d_in[21];
    float* out = (float*)d_out;

    // workspace layout (u64 units); p1..p5 are zero-padded bit maps
    u64* ws   = (u64*)d_ws;
    u64* wp2  = ws;               // 9*2*128  = 2304
    u64* wp3  = wp2 + 2304;       // 9*2*256  = 4608
    u64* wp4  = wp3 + 4608;       // 9*4*256  = 9216
    u64* wp5  = wp4 + 9216;       // 9*4*512  = 18432
    u64* wp6  = wp5 + 18432;      // 9*8*512  = 36864
    int* corr = (int*)(wp6 + 36864);   // 14976 ints = 7488 u64
    u64* p1   = wp6 + 36864 + 7488;    // 128*34*34*2 = 295936
    u64* p2   = p1 + 295936;      // 128*18*18*2 = 82944
    u64* p3   = p2 + 82944;       // 128*18*18*4 = 165888
    u64* p4   = p3 + 165888;      // 128*10*10*4 = 51200
    u64* p5   = p4 + 51200;       // 128*10*10*8 = 102400
    float* h6 = (float*)(p5 + 102400);  // 128*4*4*512 floats = 4 MB
    const int NPAD = 295936 + 82944 + 165888 + 51200 + 102400;  // 698368

    int* c2 = corr + 0;
    int* c3 = corr + 1152;
    int* c4 = corr + 3456;
    int* c5 = corr + 5760;
    int* c6 = corr + 10368;

    // prep: zero maps + pack weights + correction popcounts
    // waves: 71424 pack + 14976 corr = 86400 -> 21600 blocks, + 1024 zero
    prep_kernel<<<1024 + 21600, 256, 0, stream>>>(
        w2, w3, w4, w5, w6, wp2, wp3, wp4, wp5, wp6, corr, p1, NPAD);

    // conv1 + bn1 -> p1 (padded)
    conv1_pack_kernel<<<128*32*4, 128, 0, stream>>>(x, w1, b1, bn1s, bn1b, p1);

    // binary layers: 4096 waves each = 1024 blocks of 256
    bconv5_kernel<2,32,32,128,true, 64,true ><<<1024, 256, 0, stream>>>(p1, wp2, c2, bn2s, bn2b, p2, nullptr);
    bconv5_kernel<2,16,16,256,false,32,true ><<<1024, 256, 0, stream>>>(p2, wp3, c3, bn3s, bn3b, p3, nullptr);
    bconv5_kernel<4,16,16,256,true, 32,true ><<<1024, 256, 0, stream>>>(p3, wp4, c4, bn4s, bn4b, p4, nullptr);
    bconv5_kernel<4,8,8,  512,false,16,true ><<<1024, 256, 0, stream>>>(p4, wp5, c5, bn5s, bn5b, p5, nullptr);
    bconv5_kernel<8,8,8,  512,true, 16,false><<<1024, 256, 0, stream>>>(p5, wp6, c6, bn6s, bn6b, nullptr, h6);

    // dense + softmax : 2048 rows, one wave each
    dense_softmax_kernel<<<512, 256, 0, stream>>>(h6, dw, db, out);
}

// Round 7
// 354.806 us; speedup vs baseline: 1.1683x; 1.1683x over previous
//
#include <hip/hip_runtime.h>
#include <cstdint>
#include <math.h>

typedef unsigned long long u64;

// ---------------------------------------------------------------------------
// Activation bit-maps are CW-PLANE-MAJOR and zero-padded:
//   map[((cw*128 + b)*Hp + y)*Wp + x],  Hp=H+2, Wp=W+2, halo = 0
// Weights packed COMPLEMENTED, per-oc contiguous:
//   wq[((oc*WI + cw)*9 + tap],  bit i = !(w[tap][cw*64+i][oc] > 0)
// meta[oc*12 + k]: k=0..3 -> A,B,C,D (top/bot/left/right orig-popcount sums)
//                  k=4..7 -> p0,p2,p6,p8 (corner taps), k=8 -> ithr
// ---------------------------------------------------------------------------

__global__ void zero_kernel(u64* __restrict__ p, int n) {
    int i = blockIdx.x * blockDim.x + threadIdx.x;
    int stride = gridDim.x * blockDim.x;
    for (; i < n; i += stride) p[i] = 0;
}

// ---------------------------------------------------------------------------
// pack: one wave per (layer, oc, tap, cw) -> one complemented u64 mask
// ---------------------------------------------------------------------------
__global__ __launch_bounds__(256) void pack_kernel(
        const float* __restrict__ w2, const float* __restrict__ w3,
        const float* __restrict__ w4, const float* __restrict__ w5,
        const float* __restrict__ w6,
        u64* __restrict__ wq2, u64* __restrict__ wq3, u64* __restrict__ wq4,
        u64* __restrict__ wq5, u64* __restrict__ wq6) {
    int wid = (blockIdx.x * 256 + threadIdx.x) >> 6;
    int lane = threadIdx.x & 63;
    const float* w; u64* wq; int Wi, Cout, base;
    if      (wid <  2304) { w = w2; wq = wq2; Wi = 2; Cout = 128; base = 0; }
    else if (wid <  6912) { w = w3; wq = wq3; Wi = 2; Cout = 256; base = 2304; }
    else if (wid < 16128) { w = w4; wq = wq4; Wi = 4; Cout = 256; base = 6912; }
    else if (wid < 34560) { w = w5; wq = wq5; Wi = 4; Cout = 512; base = 16128; }
    else if (wid < 71424) { w = w6; wq = wq6; Wi = 8; Cout = 512; base = 34560; }
    else return;
    int id = wid - base;
    int oc = id % Cout;
    int tw = id / Cout;            // tap*Wi + cw
    int tap = tw / Wi, cw = tw % Wi;
    int Cin = Wi * 64;
    float v = w[((size_t)tap * Cin + cw * 64 + lane) * Cout + oc];
    u64 mask = __ballot(!(v > 0.0f));
    if (lane == 0) wq[((size_t)oc * Wi + cw) * 9 + tap] = mask;
}

// ---------------------------------------------------------------------------
// meta: one wave per oc (all 5 layers, 1664 waves). Lanes 0..8 = taps:
// P_t = #(orig w>0) = 64*WI - sum_cw popcount(complemented). Lane 0 stores
// the 8 padding-correction sums and the integer threshold
// ithr = floor(-bias/scale) (sentinel -2^29 when bias>0 -> bit always 1).
// ---------------------------------------------------------------------------
__global__ __launch_bounds__(256) void meta_kernel(
        const u64* __restrict__ wq2, const u64* __restrict__ wq3,
        const u64* __restrict__ wq4, const u64* __restrict__ wq5,
        const u64* __restrict__ wq6,
        const float* s2, const float* b2, const float* s3, const float* b3,
        const float* s4, const float* b4, const float* s5, const float* b5,
        const float* s6, const float* b6,
        int* __restrict__ mt) {
    int wid = (blockIdx.x * 256 + threadIdx.x) >> 6;
    int lane = threadIdx.x & 63;
    if (wid >= 1664) return;
    const u64* wq; int WI, oc, mbase; const float* sc; const float* bi;
    if      (wid <  128) { wq = wq2; WI = 2; oc = wid;        mbase = 0;     sc = s2; bi = b2; }
    else if (wid <  384) { wq = wq3; WI = 2; oc = wid - 128;  mbase = 1536;  sc = s3; bi = b3; }
    else if (wid <  640) { wq = wq4; WI = 4; oc = wid - 384;  mbase = 4608;  sc = s4; bi = b4; }
    else if (wid < 1152) { wq = wq5; WI = 4; oc = wid - 640;  mbase = 7680;  sc = s5; bi = b5; }
    else                 { wq = wq6; WI = 8; oc = wid - 1152; mbase = 13824; sc = s6; bi = b6; }
    int P = 0;
    if (lane < 9) {
        int s = 0;
        for (int cw = 0; cw < WI; cw++)
            s += (int)__popcll(wq[((size_t)oc * WI + cw) * 9 + lane]);
        P = 64 * WI - s;
    }
    int p0 = __shfl(P, 0, 64), p1 = __shfl(P, 1, 64), p2 = __shfl(P, 2, 64);
    int p3 = __shfl(P, 3, 64), p5 = __shfl(P, 5, 64);
    int p6 = __shfl(P, 6, 64), p7 = __shfl(P, 7, 64), p8 = __shfl(P, 8, 64);
    if (lane == 0) {
        int* mo = mt + mbase + oc * 12;
        mo[0] = p0 + p1 + p2;      // top
        mo[1] = p6 + p7 + p8;      // bottom
        mo[2] = p0 + p3 + p6;      // left
        mo[3] = p2 + p5 + p8;      // right
        mo[4] = p0; mo[5] = p2; mo[6] = p6; mo[7] = p8;
        double tneg = -(double)bi[oc] / (double)sc[oc];
        mo[8] = (tneg < 0.0) ? -(1 << 29) : (int)floor(tneg);
    }
}

// ---------------------------------------------------------------------------
// conv1 (float, 3->128) + b1 + relu + bn1 -> sign bits into plane-major
// padded p1. Weights in VGPRs, 8 px/thread sliding window. Double
// accumulation: sign decisions feed 5 binary layers; must be exact.
// ---------------------------------------------------------------------------
__global__ __launch_bounds__(128) void conv1_pack_kernel(
        const float* __restrict__ x, const float* __restrict__ w1,
        const float* __restrict__ b1, const float* __restrict__ s1,
        const float* __restrict__ bb1, u64* __restrict__ p1) {
    const int t = threadIdx.x;
    const int oc = t;
    const int bx = blockIdx.x;
    const int xseg = (bx & 3) << 3;    // 0,8,16,24
    const int y = (bx >> 2) & 31;
    const int b = bx >> 7;

    double wreg[27];
    #pragma unroll
    for (int k = 0; k < 27; k++) wreg[k] = (double)w1[k * 128 + oc];
    const double b1v = (double)b1[oc];
    const double tneg = -(double)bb1[oc] / (double)s1[oc];
    const bool always = tneg < 0.0;
    const double thr = tneg - b1v;

    double acc[8];
    #pragma unroll
    for (int i = 0; i < 8; i++) acc[i] = 0.0;

    #pragma unroll
    for (int ky = 0; ky < 3; ky++) {
        int iy = y - 1 + ky;
        if (iy < 0 || iy > 31) continue;
        #pragma unroll
        for (int col = 0; col < 10; col++) {
            int ix = xseg - 1 + col;
            if (ix < 0 || ix > 31) continue;
            const float* xp = x + ((b * 32 + iy) * 32 + ix) * 3;
            #pragma unroll
            for (int c = 0; c < 3; c++) {
                double xv = (double)xp[c];
                #pragma unroll
                for (int kx = 0; kx < 3; kx++) {
                    int px = col - kx;
                    if (px >= 0 && px < 8)
                        acc[px] += xv * wreg[(ky * 3 + kx) * 3 + c];
                }
            }
        }
    }
    const int w = t >> 6;   // cw plane
    #pragma unroll
    for (int px = 0; px < 8; px++) {
        bool bit = always || (acc[px] > thr);
        u64 m = __ballot(bit);
        if ((t & 63) == 0)
            p1[(((size_t)w * 128 + b) * 34 + y + 1) * 34 + xseg + px + 1] = m;
    }
}

// ---------------------------------------------------------------------------
// Binary conv v6 — lane = pixel, cw-outer streaming.
// One wave = 8x8 pre-pool tile x OCG channels. Per cw: act[9] (18 VGPR)
// loaded once per lane (plane-major -> coalesced); inner o-loop fully
// unrolled, weights s_load'ed at imm offsets (SMEM pipe, zero VALU);
// dot = xor + fused v_bcnt, m[OCG] VGPR-resident.
// Epilogue: d = 2*(m+S) - 64*WI*(9+n_oob); bit = d > ithr (int cmp);
// pooled mask = OR over window via 2 shfl_xor after the loop.
// ---------------------------------------------------------------------------
template<int WI, int H, int W, int COUT, bool POOL, int OCG, bool BITOUT>
__global__ __launch_bounds__(256, 4) void bconv6_kernel(
        const u64* __restrict__ in, const u64* __restrict__ wq,
        const int* __restrict__ mt,
        const float* __restrict__ bns, const float* __restrict__ bnb,
        u64* __restrict__ outb, float* __restrict__ outf) {
    constexpr int Hp = H + 2, Wp = W + 2;
    constexpr int Ho = POOL ? H / 2 : H;
    constexpr int Wo = POOL ? W / 2 : W;
    constexpr int TX = W / 8;
    constexpr int TILES = (H / 8) * (W / 8);
    constexpr int NG = COUT / OCG;

    const int lane = threadIdx.x & 63;
    int wid = (blockIdx.x * blockDim.x + threadIdx.x) >> 6;
    wid = __builtin_amdgcn_readfirstlane(wid);
    const int g = wid % NG;
    int tb = wid / NG;
    const int tile = tb % TILES;
    const int b = tb / TILES;
    if (b >= 128) return;
    const int ly = lane >> 3, lx = lane & 7;
    const int py = (tile / TX) * 8 + ly;
    const int px = (tile % TX) * 8 + lx;
    const int oc0 = g * OCG;

    // per-lane edge flags / padding base
    const int ft = (py == 0), fb = (py == H - 1);
    const int fl = (px == 0), fr = (px == W - 1);
    const int ctl = ft & fl, ctr = ft & fr, cbl = fb & fl, cbr = fb & fr;
    const int n_oob = 3 * (ft + fb + fl + fr) - ctl - ctr - cbl - cbr;
    const int dbase = -64 * WI * (9 + n_oob);
    const bool anyedge = __ballot(ft | fb | fl | fr) != 0;

    int m[OCG];
    #pragma unroll
    for (int o = 0; o < OCG; o++) m[o] = 0;

    const u64* ab = in + ((size_t)b * Hp + py) * Wp + px;   // plane 0 base
    const u64* wb0 = wq + (size_t)oc0 * WI * 9;

    #pragma unroll 1
    for (int cw = 0; cw < WI; cw++) {
        const u64* ap = ab + (size_t)cw * (128 * Hp * Wp);
        u64 act[9];
        #pragma unroll
        for (int ky = 0; ky < 3; ky++)
            #pragma unroll
            for (int kx = 0; kx < 3; kx++)
                act[ky * 3 + kx] = ap[ky * Wp + kx];
        const u64* wb = wb0 + (size_t)cw * 9;
        #pragma unroll
        for (int o = 0; o < OCG; o++) {
            const u64* wl = wb + (size_t)o * (WI * 9);   // uniform -> s_load
            int a0 = m[o], a1 = 0, a2 = 0, a3 = 0;
            #pragma unroll
            for (int t9 = 0; t9 < 9; t9++) {
                u64 xo = act[t9] ^ wl[t9];
                int lo = __builtin_popcount((unsigned)xo);
                int hi = __builtin_popcount((unsigned)(xo >> 32));
                if (t9 & 1) { a1 = lo + a1; a3 = hi + a3; }
                else        { a0 = lo + a0; a2 = hi + a2; }
            }
            m[o] = (a0 + a2) + (a1 + a3);
        }
    }

    // ---- epilogue ----
    const bool master = POOL ? (((ly | lx) & 1) == 0) : true;
    const int opy = POOL ? (py >> 1) : py, opx = POOL ? (px >> 1) : px;
    unsigned mask = 0;

    #pragma unroll
    for (int o = 0; o < OCG; o++) {
        const int* mo = mt + (size_t)(oc0 + o) * 12;
        int d;
        if (anyedge) {
            int S = ft * mo[0] + fb * mo[1] + fl * mo[2] + fr * mo[3]
                  - ctl * mo[4] - ctr * mo[5] - cbl * mo[6] - cbr * mo[7];
            d = 2 * (m[o] + S) + dbase;
        } else {
            d = 2 * m[o] - 64 * WI * 9;
        }
        if constexpr (BITOUT) {
            mask |= (unsigned)(d > mo[8]) << o;
        } else {
            int dm = max(d, __shfl_xor(d, 1, 64));
            int dp = max(dm, __shfl_xor(dm, 8, 64));
            int pmax = dp > 0 ? dp : 0;
            float h = (float)pmax * bns[oc0 + o] + bnb[oc0 + o];
            if (master)
                outf[(size_t)((b * 4 + opy) * 4 + opx) * 512 + oc0 + o] = h;
        }
    }

    if constexpr (BITOUT) {
        if constexpr (POOL) {
            mask |= __shfl_xor(mask, 1, 64);
            mask |= __shfl_xor(mask, 8, 64);
        }
        if (master) {
            size_t idx = (((size_t)(oc0 >> 6) * 128 + b) * (Ho + 2) + opy + 1)
                         * (Wo + 2) + opx + 1;
            char* bp = (char*)(outb + idx) + ((oc0 & 63) >> 3);
            if constexpr (OCG == 32) *(unsigned*)bp = mask;
            else *(unsigned short*)bp = (unsigned short)mask;
        }
    }
}

// ---------------------------------------------------------------------------
// Dense (512x10) + softmax. One wave per row. 2048 rows.
// ---------------------------------------------------------------------------
__global__ __launch_bounds__(256) void dense_softmax_kernel(
        const float* __restrict__ h6, const float* __restrict__ dw,
        const float* __restrict__ db, float* __restrict__ out) {
    int lane = threadIdx.x & 63;
    int r = (blockIdx.x * blockDim.x + threadIdx.x) >> 6;
    if (r >= 2048) return;
    const float* hr = h6 + (size_t)r * 512;
    float part[10];
    #pragma unroll
    for (int d = 0; d < 10; d++) part[d] = 0.f;
    #pragma unroll
    for (int k = 0; k < 8; k++) {
        int c = lane + 64 * k;
        float hv = hr[c];
        const float* dwr = dw + c * 10;
        #pragma unroll
        for (int d = 0; d < 10; d++) part[d] += hv * dwr[d];
    }
    #pragma unroll
    for (int off = 32; off >= 1; off >>= 1) {
        #pragma unroll
        for (int d = 0; d < 10; d++) part[d] += __shfl_down(part[d], off, 64);
    }
    if (lane == 0) {
        float logits[10];
        float mx = -1e30f;
        #pragma unroll
        for (int d = 0; d < 10; d++) { logits[d] = part[d] + db[d]; mx = fmaxf(mx, logits[d]); }
        float se = 0.f;
        #pragma unroll
        for (int d = 0; d < 10; d++) { logits[d] = expf(logits[d] - mx); se += logits[d]; }
        float inv = 1.f / se;
        #pragma unroll
        for (int d = 0; d < 10; d++) out[(size_t)r * 10 + d] = logits[d] * inv;
    }
}

// ---------------------------------------------------------------------------
extern "C" void kernel_launch(void* const* d_in, const int* in_sizes, int n_in,
                              void* d_out, int out_size, void* d_ws, size_t ws_size,
                              hipStream_t stream) {
    const float* x    = (const float*)d_in[0];
    const float* w1   = (const float*)d_in[1];
    const float* b1   = (const float*)d_in[2];
    const float* w2   = (const float*)d_in[3];
    const float* w3   = (const float*)d_in[4];
    const float* w4   = (const float*)d_in[5];
    const float* w5   = (const float*)d_in[6];
    const float* w6   = (const float*)d_in[7];
    const float* bn1s = (const float*)d_in[8];
    const float* bn1b = (const float*)d_in[9];
    const float* bn2s = (const float*)d_in[10];
    const float* bn2b = (const float*)d_in[11];
    const float* bn3s = (const float*)d_in[12];
    const float* bn3b = (const float*)d_in[13];
    const float* bn4s = (const float*)d_in[14];
    const float* bn4b = (const float*)d_in[15];
    const float* bn5s = (const float*)d_in[16];
    const float* bn5b = (const float*)d_in[17];
    const float* bn6s = (const float*)d_in[18];
    const float* bn6b = (const float*)d_in[19];
    const float* dw   = (const float*)d_in[20];
    const float* db   = (const float*)d_in[21];
    float* out = (float*)d_out;

    // workspace (u64 units)
    u64* ws   = (u64*)d_ws;
    u64* wq2  = ws;                    // 2304
    u64* wq3  = ws + 2304;             // 4608
    u64* wq4  = ws + 6912;             // 9216
    u64* wq5  = ws + 16128;            // 18432
    u64* wq6  = ws + 34560;            // 36864
    int* mt   = (int*)(ws + 71424);    // 19968 ints = 9984 u64
    u64* p1   = ws + 81408;            // 2*128*34*34 = 295936
    u64* p2   = ws + 377344;           // 2*128*18*18 = 82944
    u64* p3   = ws + 460288;           // 4*128*18*18 = 165888
    u64* p4   = ws + 626176;           // 4*128*10*10 = 51200
    u64* p5   = ws + 677376;           // 8*128*10*10 = 102400
    float* h6 = (float*)(ws + 779776); // 128*4*4*512 floats = 524288 u64
    const int NPAD = 295936 + 82944 + 165888 + 51200 + 102400;  // 698368

    int* mt2 = mt + 0;
    int* mt3 = mt + 1536;
    int* mt4 = mt + 4608;
    int* mt5 = mt + 7680;
    int* mt6 = mt + 13824;

    zero_kernel<<<1024, 256, 0, stream>>>(p1, NPAD);
    pack_kernel<<<17856, 256, 0, stream>>>(w2, w3, w4, w5, w6,
                                           wq2, wq3, wq4, wq5, wq6);
    meta_kernel<<<416, 256, 0, stream>>>(wq2, wq3, wq4, wq5, wq6,
        bn2s, bn2b, bn3s, bn3b, bn4s, bn4b, bn5s, bn5b, bn6s, bn6b, mt);

    conv1_pack_kernel<<<128*32*4, 128, 0, stream>>>(x, w1, b1, bn1s, bn1b, p1);

    bconv6_kernel<2,32,32,128,true, 32,true ><<<2048, 256, 0, stream>>>(p1, wq2, mt2, nullptr, nullptr, p2, nullptr);
    bconv6_kernel<2,16,16,256,false,32,true ><<<1024, 256, 0, stream>>>(p2, wq3, mt3, nullptr, nullptr, p3, nullptr);
    bconv6_kernel<4,16,16,256,true, 16,true ><<<2048, 256, 0, stream>>>(p3, wq4, mt4, nullptr, nullptr, p4, nullptr);
    bconv6_kernel<4,8,8,  512,false,16,true ><<<1024, 256, 0, stream>>>(p4, wq5, mt5, nullptr, nullptr, p5, nullptr);
    bconv6_kernel<8,8,8,  512,true, 16,false><<<1024, 256, 0, stream>>>(p5, wq6, mt6, bn6s, bn6b, nullptr, h6);

    dense_softmax_kernel<<<512, 256, 0, stream>>>(h6, dw, db, out);
}